// Round 1
// baseline (851.484 us; speedup 1.0000x reference)
//
#include <hip/hip_runtime.h>
#include <hip/hip_bf16.h>

// Problem constants (from reference)
#define D_EMB    512
#define D4       128        // D_EMB/4 float4 per row
#define NCOMP    1024
#define NDOSE    8
#define NSEG     (NCOMP * NDOSE)   // 8192
#define MARGIN_F 0.1f

// ---------------------------------------------------------------------------
// Kernel 1: column sums of embeddings -> mu_sum[512] (atomic accumulate)
// Block 256 threads: 128 float4-columns x 2 row-subgroups. Grid-stride rows.
// ---------------------------------------------------------------------------
__global__ __launch_bounds__(256) void colsum_kernel(
    const float* __restrict__ emb, float* __restrict__ mu_sum, int n_rows)
{
    const int c4   = threadIdx.x & 127;   // float4 column index
    const int rsub = threadIdx.x >> 7;    // 0..1
    const float4* __restrict__ E = (const float4*)emb;

    float4 acc = make_float4(0.f, 0.f, 0.f, 0.f);
    const int stride = gridDim.x * 2;
    #pragma unroll 4
    for (int r = blockIdx.x * 2 + rsub; r < n_rows; r += stride) {
        float4 v = E[(size_t)r * D4 + c4];
        acc.x += v.x; acc.y += v.y; acc.z += v.z; acc.w += v.w;
    }

    __shared__ float4 part[256];
    part[threadIdx.x] = acc;
    __syncthreads();
    if (threadIdx.x < 128) {
        float4 a = part[threadIdx.x];
        float4 b = part[threadIdx.x + 128];
        const int c = c4 * 4;
        atomicAdd(&mu_sum[c + 0], a.x + b.x);
        atomicAdd(&mu_sum[c + 1], a.y + b.y);
        atomicAdd(&mu_sum[c + 2], a.z + b.z);
        atomicAdd(&mu_sum[c + 3], a.w + b.w);
    }
}

// ---------------------------------------------------------------------------
// Kernel 2: origin = (mu_sum/N) / max(||mu_sum/N||, 1e-12). One block, 512 thr.
// ---------------------------------------------------------------------------
__global__ __launch_bounds__(512) void normalize_kernel(
    const float* __restrict__ mu_sum, float* __restrict__ origin, float inv_n)
{
    const int d = threadIdx.x;            // 0..511
    float mu = mu_sum[d] * inv_n;
    float sq = mu * mu;
    // wave reduce (64 lanes)
    #pragma unroll
    for (int off = 32; off; off >>= 1) sq += __shfl_xor(sq, off, 64);
    __shared__ float ws[8];
    const int wave = d >> 6, lane = d & 63;
    if (lane == 0) ws[wave] = sq;
    __syncthreads();
    float ss = 0.f;
    #pragma unroll
    for (int i = 0; i < 8; ++i) ss += ws[i];
    const float norm = fmaxf(sqrtf(ss), 1e-12f);
    origin[d] = mu / norm;
}

// ---------------------------------------------------------------------------
// Kernel 3: per-row dist = 1 - e_i . origin, atomic segment accumulation.
// One wave (64 lanes) per row; lane handles float4 cols {lane, lane+64}.
// ---------------------------------------------------------------------------
__global__ __launch_bounds__(256) void dist_seg_kernel(
    const float* __restrict__ emb, const float* __restrict__ origin,
    const int* __restrict__ comp, const int* __restrict__ dose,
    float* __restrict__ seg_sum, float* __restrict__ seg_cnt, int n_rows)
{
    const int lane = threadIdx.x & 63;
    const int wave = threadIdx.x >> 6;
    const int waves_per_blk = blockDim.x >> 6;
    const int wglob  = blockIdx.x * waves_per_blk + wave;
    const int wtotal = gridDim.x * waves_per_blk;

    const float4* __restrict__ E = (const float4*)emb;
    const float4* __restrict__ O = (const float4*)origin;
    const float4 o0 = O[lane];
    const float4 o1 = O[lane + 64];

    for (int r = wglob; r < n_rows; r += wtotal) {
        const float4* row = E + (size_t)r * D4;
        float4 v0 = row[lane];
        float4 v1 = row[lane + 64];
        float p = v0.x * o0.x + v0.y * o0.y + v0.z * o0.z + v0.w * o0.w
                + v1.x * o1.x + v1.y * o1.y + v1.z * o1.z + v1.w * o1.w;
        #pragma unroll
        for (int off = 32; off; off >>= 1) p += __shfl_xor(p, off, 64);
        if (lane == 0) {
            const float dist = 1.0f - p;
            const int s = comp[r] * NDOSE + dose[r];
            atomicAdd(&seg_sum[s], dist);
            atomicAdd(&seg_cnt[s], 1.0f);
        }
    }
}

// ---------------------------------------------------------------------------
// Kernel 4: ordinal margin epilogue over 1024 compounds x 8 doses -> scalar.
// One block, 1024 threads (one compound each), block reduce.
// ---------------------------------------------------------------------------
__global__ __launch_bounds__(1024) void epilogue_kernel(
    const float* __restrict__ seg_sum, const float* __restrict__ seg_cnt,
    float* __restrict__ out)
{
    const int c = threadIdx.x;            // compound id, 0..1023
    float loss = 0.f, cnt = 0.f;
    {
        float last_mean = 0.f;
        bool  last_valid = false;
        #pragma unroll
        for (int d = 0; d < NDOSE; ++d) {
            const float s = seg_sum[c * NDOSE + d];
            const float n = seg_cnt[c * NDOSE + d];
            const bool pres = (n > 0.f);
            const float mean = s / fmaxf(n, 1.f);
            if (pres && last_valid) {
                loss += fmaxf(MARGIN_F - (mean - last_mean), 0.f);
                cnt  += 1.f;
            }
            if (pres) { last_mean = mean; last_valid = true; }
        }
    }
    __shared__ float sl[1024];
    __shared__ float sc[1024];
    sl[c] = loss; sc[c] = cnt;
    __syncthreads();
    #pragma unroll
    for (int off = 512; off; off >>= 1) {
        if (c < off) { sl[c] += sl[c + off]; sc[c] += sc[c + off]; }
        __syncthreads();
    }
    if (c == 0) out[0] = (sc[0] > 0.f) ? (sl[0] / fmaxf(sc[0], 1.f)) : 0.f;
}

// ---------------------------------------------------------------------------
extern "C" void kernel_launch(void* const* d_in, const int* in_sizes, int n_in,
                              void* d_out, int out_size, void* d_ws, size_t ws_size,
                              hipStream_t stream)
{
    const float* emb  = (const float*)d_in[0];
    const int*   comp = (const int*)d_in[1];
    const int*   dose = (const int*)d_in[2];
    float*       out  = (float*)d_out;

    const int n = in_sizes[1];            // N rows

    // workspace layout (floats): seg_sum[8192] | seg_cnt[8192] | mu_sum[512] | origin[512]
    float* seg_sum = (float*)d_ws;
    float* seg_cnt = seg_sum + NSEG;
    float* mu_sum  = seg_cnt + NSEG;
    float* origin  = mu_sum + D_EMB;

    // zero accumulators (seg_sum, seg_cnt, mu_sum); origin fully overwritten
    hipMemsetAsync(d_ws, 0, (size_t)(2 * NSEG + D_EMB) * sizeof(float), stream);

    colsum_kernel<<<1024, 256, 0, stream>>>(emb, mu_sum, n);
    normalize_kernel<<<1, 512, 0, stream>>>(mu_sum, origin, 1.0f / (float)n);
    dist_seg_kernel<<<2048, 256, 0, stream>>>(emb, origin, comp, dose,
                                              seg_sum, seg_cnt, n);
    epilogue_kernel<<<1, 1024, 0, stream>>>(seg_sum, seg_cnt, out);
}

// Round 3
// 777.682 us; speedup vs baseline: 1.0949x; 1.0949x over previous
//
#include <hip/hip_runtime.h>
#include <hip/hip_bf16.h>

// Problem constants (from reference)
#define D_EMB    512
#define D4       128                 // D_EMB/4 float4 per row
#define NCOMP    1024
#define NDOSE    8
#define NSEG     (NCOMP * NDOSE)     // 8192
#define MARGIN_F 0.1f

typedef unsigned int uint32;

// ---------------------------------------------------------------------------
// K1: histogram of segment ids. LDS-local then merge to global.
// ---------------------------------------------------------------------------
__global__ __launch_bounds__(256) void hist_kernel(
    const int* __restrict__ comp, const int* __restrict__ dose,
    uint32* __restrict__ hist, int n)
{
    __shared__ uint32 lh[NSEG];
    for (int i = threadIdx.x; i < NSEG; i += blockDim.x) lh[i] = 0;
    __syncthreads();
    const int stride = gridDim.x * blockDim.x;
    for (int r = blockIdx.x * blockDim.x + threadIdx.x; r < n; r += stride) {
        const int s = comp[r] * NDOSE + dose[r];
        atomicAdd(&lh[s], 1u);
    }
    __syncthreads();
    for (int i = threadIdx.x; i < NSEG; i += blockDim.x) {
        const uint32 v = lh[i];
        if (v) atomicAdd(&hist[i], v);
    }
}

// ---------------------------------------------------------------------------
// K2: exclusive scan of hist[8192] -> off[], and init cur[]=off[].
// One block, 1024 threads, 8 segments/thread.
// ---------------------------------------------------------------------------
__global__ __launch_bounds__(1024) void scan_kernel(
    const uint32* __restrict__ hist, uint32* __restrict__ off,
    uint32* __restrict__ cur)
{
    const int t = threadIdx.x;
    uint32 v[8];
    uint32 tot = 0;
    #pragma unroll
    for (int j = 0; j < 8; ++j) { v[j] = hist[t * 8 + j]; tot += v[j]; }

    __shared__ uint32 sums[1024];
    sums[t] = tot;
    __syncthreads();
    for (int o = 1; o < 1024; o <<= 1) {
        uint32 add = (t >= o) ? sums[t - o] : 0u;
        __syncthreads();
        sums[t] += add;
        __syncthreads();
    }
    uint32 run = sums[t] - tot;     // exclusive base for this thread's 8 segs
    #pragma unroll
    for (int j = 0; j < 8; ++j) {
        off[t * 8 + j] = run;
        cur[t * 8 + j] = run;
        run += v[j];
    }
}

// ---------------------------------------------------------------------------
// K3: scatter row indices into segment-sorted order.
// ---------------------------------------------------------------------------
__global__ __launch_bounds__(256) void scatter_kernel(
    const int* __restrict__ comp, const int* __restrict__ dose,
    uint32* __restrict__ cur, uint32* __restrict__ perm, int n)
{
    const int stride = gridDim.x * blockDim.x;
    for (int r = blockIdx.x * blockDim.x + threadIdx.x; r < n; r += stride) {
        const int s = comp[r] * NDOSE + dose[r];
        const uint32 pos = atomicAdd(&cur[s], 1u);
        perm[pos] = (uint32)r;
    }
}

// ---------------------------------------------------------------------------
// K4: per-segment vector sums S[s][512]. One block per segment, atomic-free.
// 256 threads = 128 float4 columns x 2 row-subgroups. THE 512 MiB pass.
// ---------------------------------------------------------------------------
__global__ __launch_bounds__(256) void segsum_kernel(
    const float* __restrict__ emb, const uint32* __restrict__ off,
    const uint32* __restrict__ hist, const uint32* __restrict__ perm,
    float* __restrict__ S)
{
    const int s    = blockIdx.x;
    const int c4   = threadIdx.x & 127;
    const int rsub = threadIdx.x >> 7;
    const uint32 beg = off[s];
    const uint32 cnt = hist[s];
    const float4* __restrict__ E = (const float4*)emb;

    float4 acc = make_float4(0.f, 0.f, 0.f, 0.f);
    for (uint32 i = rsub; i < cnt; i += 2) {
        const uint32 r = perm[beg + i];
        const float4 v = E[(size_t)r * D4 + c4];
        acc.x += v.x; acc.y += v.y; acc.z += v.z; acc.w += v.w;
    }
    __shared__ float4 part[256];
    part[threadIdx.x] = acc;
    __syncthreads();
    if (threadIdx.x < 128) {
        const float4 a = part[threadIdx.x];
        const float4 b = part[threadIdx.x + 128];
        float4 o;
        o.x = a.x + b.x; o.y = a.y + b.y; o.z = a.z + b.z; o.w = a.w + b.w;
        ((float4*)S)[(size_t)s * D4 + c4] = o;
    }
}

// ---------------------------------------------------------------------------
// K5: mu_sum[512] = sum over segments of S  (coalesced, atomic merge)
// ---------------------------------------------------------------------------
__global__ __launch_bounds__(128) void musum_kernel(
    const float* __restrict__ S, float* __restrict__ mu_sum)
{
    const int c4 = threadIdx.x;          // 0..127
    const float4* __restrict__ S4 = (const float4*)S;
    float4 acc = make_float4(0.f, 0.f, 0.f, 0.f);
    for (int s = blockIdx.x; s < NSEG; s += gridDim.x) {
        const float4 v = S4[(size_t)s * D4 + c4];
        acc.x += v.x; acc.y += v.y; acc.z += v.z; acc.w += v.w;
    }
    const int c = c4 * 4;
    atomicAdd(&mu_sum[c + 0], acc.x);
    atomicAdd(&mu_sum[c + 1], acc.y);
    atomicAdd(&mu_sum[c + 2], acc.z);
    atomicAdd(&mu_sum[c + 3], acc.w);
}

// ---------------------------------------------------------------------------
// K6: origin = (mu_sum/N) / max(||mu_sum/N||, 1e-12). One block, 512 thr.
// ---------------------------------------------------------------------------
__global__ __launch_bounds__(512) void normalize_kernel(
    const float* __restrict__ mu_sum, float* __restrict__ origin, float inv_n)
{
    const int d = threadIdx.x;
    float mu = mu_sum[d] * inv_n;
    float sq = mu * mu;
    #pragma unroll
    for (int o = 32; o; o >>= 1) sq += __shfl_xor(sq, o, 64);
    __shared__ float ws[8];
    const int wave = d >> 6, lane = d & 63;
    if (lane == 0) ws[wave] = sq;
    __syncthreads();
    float ss = 0.f;
    #pragma unroll
    for (int i = 0; i < 8; ++i) ss += ws[i];
    const float norm = fmaxf(sqrtf(ss), 1e-12f);
    origin[d] = mu / norm;
}

// ---------------------------------------------------------------------------
// K7: seg_mean[s] = (cnt_s - S_s . origin) / max(cnt_s, 1). One wave/segment.
// ---------------------------------------------------------------------------
__global__ __launch_bounds__(256) void dot_kernel(
    const float* __restrict__ S, const float* __restrict__ origin,
    const uint32* __restrict__ hist, float* __restrict__ seg_mean)
{
    const int lane = threadIdx.x & 63;
    const int wave = threadIdx.x >> 6;
    const int wglob = blockIdx.x * (blockDim.x >> 6) + wave;
    const int wtot  = gridDim.x * (blockDim.x >> 6);
    const float4* __restrict__ S4 = (const float4*)S;
    const float4* __restrict__ O  = (const float4*)origin;
    const float4 o0 = O[lane];
    const float4 o1 = O[lane + 64];

    for (int s = wglob; s < NSEG; s += wtot) {
        const float4 v0 = S4[(size_t)s * D4 + lane];
        const float4 v1 = S4[(size_t)s * D4 + lane + 64];
        float p = v0.x * o0.x + v0.y * o0.y + v0.z * o0.z + v0.w * o0.w
                + v1.x * o1.x + v1.y * o1.y + v1.z * o1.z + v1.w * o1.w;
        #pragma unroll
        for (int o = 32; o; o >>= 1) p += __shfl_xor(p, o, 64);
        if (lane == 0) {
            const float cntf = (float)hist[s];
            seg_mean[s] = (cntf - p) / fmaxf(cntf, 1.f);
        }
    }
}

// ---------------------------------------------------------------------------
// K8: ordinal margin epilogue -> scalar. One block, 1024 threads.
// ---------------------------------------------------------------------------
__global__ __launch_bounds__(1024) void epilogue_kernel(
    const float* __restrict__ seg_mean, const uint32* __restrict__ hist,
    float* __restrict__ out)
{
    const int c = threadIdx.x;           // compound id
    float loss = 0.f, cntv = 0.f;
    {
        float last_mean = 0.f;
        bool  last_valid = false;
        #pragma unroll
        for (int d = 0; d < NDOSE; ++d) {
            const bool  pres = hist[c * NDOSE + d] > 0u;
            const float mean = seg_mean[c * NDOSE + d];
            if (pres && last_valid) {
                loss += fmaxf(MARGIN_F - (mean - last_mean), 0.f);
                cntv += 1.f;
            }
            if (pres) { last_mean = mean; last_valid = true; }
        }
    }
    __shared__ float sl[1024];
    __shared__ float sc[1024];
    sl[c] = loss; sc[c] = cntv;
    __syncthreads();
    #pragma unroll
    for (int o = 512; o; o >>= 1) {
        if (c < o) { sl[c] += sl[c + o]; sc[c] += sc[c + o]; }
        __syncthreads();
    }
    if (c == 0) out[0] = (sc[0] > 0.f) ? (sl[0] / fmaxf(sc[0], 1.f)) : 0.f;
}

// ---------------------------------------------------------------------------
extern "C" void kernel_launch(void* const* d_in, const int* in_sizes, int n_in,
                              void* d_out, int out_size, void* d_ws, size_t ws_size,
                              hipStream_t stream)
{
    const float* emb  = (const float*)d_in[0];
    const int*   comp = (const int*)d_in[1];
    const int*   dose = (const int*)d_in[2];
    float*       out  = (float*)d_out;
    const int n = in_sizes[1];

    // workspace layout:
    //   hist[8192]u32 | mu_sum[512]f   <-- zeroed together (memset below)
    //   off[8192]u32 | cur[8192]u32 | perm[n]u32 | seg_mean[8192]f |
    //   origin[512]f | S[8192*512]f
    uint32* hist    = (uint32*)d_ws;
    float*  mu_sum  = (float*)(hist + NSEG);
    uint32* off     = (uint32*)(mu_sum + D_EMB);
    uint32* cur     = off + NSEG;
    uint32* perm    = cur + NSEG;
    float*  seg_mean= (float*)(perm + n);
    float*  origin  = seg_mean + NSEG;
    float*  S       = origin + D_EMB;

    hipMemsetAsync(d_ws, 0, (size_t)(NSEG + D_EMB) * sizeof(float), stream);

    hist_kernel    <<<256, 256, 0, stream>>>(comp, dose, hist, n);
    scan_kernel    <<<1, 1024, 0, stream>>>(hist, off, cur);
    scatter_kernel <<<1024, 256, 0, stream>>>(comp, dose, cur, perm, n);
    segsum_kernel  <<<NSEG, 256, 0, stream>>>(emb, off, hist, perm, S);
    musum_kernel   <<<128, 128, 0, stream>>>(S, mu_sum);
    normalize_kernel<<<1, 512, 0, stream>>>(mu_sum, origin, 1.0f / (float)n);
    dot_kernel     <<<128, 256, 0, stream>>>(S, origin, hist, seg_mean);
    epilogue_kernel<<<1, 1024, 0, stream>>>(seg_mean, hist, out);
}

// Round 4
// 768.659 us; speedup vs baseline: 1.1078x; 1.0117x over previous
//
#include <hip/hip_runtime.h>
#include <hip/hip_bf16.h>

// Problem constants (from reference)
#define D_EMB    512
#define D4       128                 // D_EMB/4 float4 per row
#define NCOMP    1024
#define NDOSE    8
#define NSEG     (NCOMP * NDOSE)     // 8192
#define MARGIN_F 0.1f

typedef unsigned int uint32;

// ---------------------------------------------------------------------------
// K1: histogram of segment ids. LDS-local then merge to global.
// ---------------------------------------------------------------------------
__global__ __launch_bounds__(256) void hist_kernel(
    const int* __restrict__ comp, const int* __restrict__ dose,
    uint32* __restrict__ hist, int n)
{
    __shared__ uint32 lh[NSEG];
    for (int i = threadIdx.x; i < NSEG; i += blockDim.x) lh[i] = 0;
    __syncthreads();
    const int stride = gridDim.x * blockDim.x;
    for (int r = blockIdx.x * blockDim.x + threadIdx.x; r < n; r += stride) {
        const int s = comp[r] * NDOSE + dose[r];
        atomicAdd(&lh[s], 1u);
    }
    __syncthreads();
    for (int i = threadIdx.x; i < NSEG; i += blockDim.x) {
        const uint32 v = lh[i];
        if (v) atomicAdd(&hist[i], v);
    }
}

// ---------------------------------------------------------------------------
// K2: exclusive scan of hist[8192] -> off[], and init cur[]=off[].
// One block, 1024 threads, 8 segments/thread.
// ---------------------------------------------------------------------------
__global__ __launch_bounds__(1024) void scan_kernel(
    const uint32* __restrict__ hist, uint32* __restrict__ off,
    uint32* __restrict__ cur)
{
    const int t = threadIdx.x;
    uint32 v[8];
    uint32 tot = 0;
    #pragma unroll
    for (int j = 0; j < 8; ++j) { v[j] = hist[t * 8 + j]; tot += v[j]; }

    __shared__ uint32 sums[1024];
    sums[t] = tot;
    __syncthreads();
    for (int o = 1; o < 1024; o <<= 1) {
        uint32 add = (t >= o) ? sums[t - o] : 0u;
        __syncthreads();
        sums[t] += add;
        __syncthreads();
    }
    uint32 run = sums[t] - tot;     // exclusive base for this thread's 8 segs
    #pragma unroll
    for (int j = 0; j < 8; ++j) {
        off[t * 8 + j] = run;
        cur[t * 8 + j] = run;
        run += v[j];
    }
}

// ---------------------------------------------------------------------------
// K3: scatter row indices into segment-sorted order.
// ---------------------------------------------------------------------------
__global__ __launch_bounds__(256) void scatter_kernel(
    const int* __restrict__ comp, const int* __restrict__ dose,
    uint32* __restrict__ cur, uint32* __restrict__ perm, int n)
{
    const int stride = gridDim.x * blockDim.x;
    for (int r = blockIdx.x * blockDim.x + threadIdx.x; r < n; r += stride) {
        const int s = comp[r] * NDOSE + dose[r];
        const uint32 pos = atomicAdd(&cur[s], 1u);
        perm[pos] = (uint32)r;
    }
}

// ---------------------------------------------------------------------------
// K4: per-segment vector sums S[s][512]. One block per segment, atomic-free.
// 256 threads = 128 float4 columns x 2 row-subgroups. THE 512 MiB pass.
// Segment's row indices staged in LDS so the gather loop has no dependent
// uniform global load on its critical path.
// ---------------------------------------------------------------------------
#define PERM_LDS 128
__global__ __launch_bounds__(256) void segsum_kernel(
    const float* __restrict__ emb, const uint32* __restrict__ off,
    const uint32* __restrict__ hist, const uint32* __restrict__ perm,
    float* __restrict__ S)
{
    const int s    = blockIdx.x;
    const int c4   = threadIdx.x & 127;
    const int rsub = threadIdx.x >> 7;
    const uint32 beg = off[s];
    const uint32 cnt = hist[s];
    const float4* __restrict__ E = (const float4*)emb;

    __shared__ uint32 lperm[PERM_LDS];
    const uint32 staged = (cnt < (uint32)PERM_LDS) ? cnt : (uint32)PERM_LDS;
    for (uint32 i = threadIdx.x; i < staged; i += blockDim.x)
        lperm[i] = perm[beg + i];
    __syncthreads();

    float4 acc = make_float4(0.f, 0.f, 0.f, 0.f);
    uint32 i = (uint32)rsub;
    for (; i < staged; i += 2) {
        const uint32 r = lperm[i];
        const float4 v = E[(size_t)r * D4 + c4];
        acc.x += v.x; acc.y += v.y; acc.z += v.z; acc.w += v.w;
    }
    for (; i < cnt; i += 2) {    // tail fallback (cnt > 128: essentially never)
        const uint32 r = perm[beg + i];
        const float4 v = E[(size_t)r * D4 + c4];
        acc.x += v.x; acc.y += v.y; acc.z += v.z; acc.w += v.w;
    }

    __shared__ float4 part[256];
    part[threadIdx.x] = acc;
    __syncthreads();
    if (threadIdx.x < 128) {
        const float4 a = part[threadIdx.x];
        const float4 b = part[threadIdx.x + 128];
        float4 o;
        o.x = a.x + b.x; o.y = a.y + b.y; o.z = a.z + b.z; o.w = a.w + b.w;
        ((float4*)S)[(size_t)s * D4 + c4] = o;
    }
}

// ---------------------------------------------------------------------------
// K5: mu_sum[512] = sum over segments of S  (coalesced, atomic merge)
// ---------------------------------------------------------------------------
__global__ __launch_bounds__(128) void musum_kernel(
    const float* __restrict__ S, float* __restrict__ mu_sum)
{
    const int c4 = threadIdx.x;          // 0..127
    const float4* __restrict__ S4 = (const float4*)S;
    float4 acc = make_float4(0.f, 0.f, 0.f, 0.f);
    for (int s = blockIdx.x; s < NSEG; s += gridDim.x) {
        const float4 v = S4[(size_t)s * D4 + c4];
        acc.x += v.x; acc.y += v.y; acc.z += v.z; acc.w += v.w;
    }
    const int c = c4 * 4;
    atomicAdd(&mu_sum[c + 0], acc.x);
    atomicAdd(&mu_sum[c + 1], acc.y);
    atomicAdd(&mu_sum[c + 2], acc.z);
    atomicAdd(&mu_sum[c + 3], acc.w);
}

// ---------------------------------------------------------------------------
// K6: seg_mean[s] = (cnt_s - S_s . origin) / max(cnt_s, 1). One wave/segment.
// origin computed per-wave (redundantly) from mu_sum: mu = mu_sum/N,
// origin = mu / max(||mu||, 1e-12). No LDS, no extra kernel hop.
// ---------------------------------------------------------------------------
__global__ __launch_bounds__(256) void dot_kernel(
    const float* __restrict__ S, const float* __restrict__ mu_sum,
    const uint32* __restrict__ hist, float* __restrict__ seg_mean, float inv_n)
{
    const int lane = threadIdx.x & 63;
    const int wave = threadIdx.x >> 6;
    const int wglob = blockIdx.x * (blockDim.x >> 6) + wave;
    const int wtot  = gridDim.x * (blockDim.x >> 6);

    // per-wave origin computation (each lane owns float4 cols lane, lane+64)
    const float4* __restrict__ MU = (const float4*)mu_sum;
    float4 m0 = MU[lane];
    float4 m1 = MU[lane + 64];
    m0.x *= inv_n; m0.y *= inv_n; m0.z *= inv_n; m0.w *= inv_n;
    m1.x *= inv_n; m1.y *= inv_n; m1.z *= inv_n; m1.w *= inv_n;
    float sq = m0.x * m0.x + m0.y * m0.y + m0.z * m0.z + m0.w * m0.w
             + m1.x * m1.x + m1.y * m1.y + m1.z * m1.z + m1.w * m1.w;
    #pragma unroll
    for (int o = 32; o; o >>= 1) sq += __shfl_xor(sq, o, 64);
    const float inv_norm = 1.0f / fmaxf(sqrtf(sq), 1e-12f);
    float4 o0, o1;
    o0.x = m0.x * inv_norm; o0.y = m0.y * inv_norm;
    o0.z = m0.z * inv_norm; o0.w = m0.w * inv_norm;
    o1.x = m1.x * inv_norm; o1.y = m1.y * inv_norm;
    o1.z = m1.z * inv_norm; o1.w = m1.w * inv_norm;

    const float4* __restrict__ S4 = (const float4*)S;
    for (int s = wglob; s < NSEG; s += wtot) {
        const float4 v0 = S4[(size_t)s * D4 + lane];
        const float4 v1 = S4[(size_t)s * D4 + lane + 64];
        float p = v0.x * o0.x + v0.y * o0.y + v0.z * o0.z + v0.w * o0.w
                + v1.x * o1.x + v1.y * o1.y + v1.z * o1.z + v1.w * o1.w;
        #pragma unroll
        for (int o = 32; o; o >>= 1) p += __shfl_xor(p, o, 64);
        if (lane == 0) {
            const float cntf = (float)hist[s];
            seg_mean[s] = (cntf - p) / fmaxf(cntf, 1.f);
        }
    }
}

// ---------------------------------------------------------------------------
// K7: ordinal margin epilogue -> scalar. One block, 1024 threads.
// ---------------------------------------------------------------------------
__global__ __launch_bounds__(1024) void epilogue_kernel(
    const float* __restrict__ seg_mean, const uint32* __restrict__ hist,
    float* __restrict__ out)
{
    const int c = threadIdx.x;           // compound id
    float loss = 0.f, cntv = 0.f;
    {
        float last_mean = 0.f;
        bool  last_valid = false;
        #pragma unroll
        for (int d = 0; d < NDOSE; ++d) {
            const bool  pres = hist[c * NDOSE + d] > 0u;
            const float mean = seg_mean[c * NDOSE + d];
            if (pres && last_valid) {
                loss += fmaxf(MARGIN_F - (mean - last_mean), 0.f);
                cntv += 1.f;
            }
            if (pres) { last_mean = mean; last_valid = true; }
        }
    }
    __shared__ float sl[1024];
    __shared__ float sc[1024];
    sl[c] = loss; sc[c] = cntv;
    __syncthreads();
    #pragma unroll
    for (int o = 512; o; o >>= 1) {
        if (c < o) { sl[c] += sl[c + o]; sc[c] += sc[c + o]; }
        __syncthreads();
    }
    if (c == 0) out[0] = (sc[0] > 0.f) ? (sl[0] / fmaxf(sc[0], 1.f)) : 0.f;
}

// ---------------------------------------------------------------------------
extern "C" void kernel_launch(void* const* d_in, const int* in_sizes, int n_in,
                              void* d_out, int out_size, void* d_ws, size_t ws_size,
                              hipStream_t stream)
{
    const float* emb  = (const float*)d_in[0];
    const int*   comp = (const int*)d_in[1];
    const int*   dose = (const int*)d_in[2];
    float*       out  = (float*)d_out;
    const int n = in_sizes[1];

    // workspace layout:
    //   hist[8192]u32 | mu_sum[512]f   <-- zeroed together (memset below)
    //   off[8192]u32 | cur[8192]u32 | perm[n]u32 | seg_mean[8192]f |
    //   (unused 512f) | S[8192*512]f
    uint32* hist    = (uint32*)d_ws;
    float*  mu_sum  = (float*)(hist + NSEG);
    uint32* off     = (uint32*)(mu_sum + D_EMB);
    uint32* cur     = off + NSEG;
    uint32* perm    = cur + NSEG;
    float*  seg_mean= (float*)(perm + n);
    float*  S       = seg_mean + NSEG + D_EMB;

    hipMemsetAsync(d_ws, 0, (size_t)(NSEG + D_EMB) * sizeof(float), stream);

    hist_kernel    <<<256, 256, 0, stream>>>(comp, dose, hist, n);
    scan_kernel    <<<1, 1024, 0, stream>>>(hist, off, cur);
    scatter_kernel <<<1024, 256, 0, stream>>>(comp, dose, cur, perm, n);
    segsum_kernel  <<<NSEG, 256, 0, stream>>>(emb, off, hist, perm, S);
    musum_kernel   <<<128, 128, 0, stream>>>(S, mu_sum);
    dot_kernel     <<<128, 256, 0, stream>>>(S, mu_sum, hist, seg_mean,
                                             1.0f / (float)n);
    epilogue_kernel<<<1, 1024, 0, stream>>>(seg_mean, hist, out);
}